// Round 3
// baseline (322.226 us; speedup 1.0000x reference)
//
#include <hip/hip_runtime.h>
#include <hip/hip_fp16.h>

#define WG 256

typedef _Float16 f16;
typedef _Float16 hv2 __attribute__((ext_vector_type(2)));
typedef _Float16 f16x4 __attribute__((ext_vector_type(4)));
typedef _Float16 f16x8 __attribute__((ext_vector_type(8)));
typedef float f32x4 __attribute__((ext_vector_type(4)));

// ============ fused A: misc (transposes + pair cvt) || edge histogram ============
__global__ __launch_bounds__(WG) void k_fusedA(const float* __restrict__ Wg,
                                               f16* __restrict__ Wgt,
                                               const float* __restrict__ W1,
                                               f16* __restrict__ W1t,
                                               const int* __restrict__ pairs,
                                               float* __restrict__ outp, int n4,
                                               const int* __restrict__ dst,
                                               int* __restrict__ deg,
                                               int* __restrict__ rank, int e,
                                               int nmisc, int necnt) {
    int b = blockIdx.x, role = b & 1, idx = b >> 1;
    if (role == 1) {  // edge histogram (atomic-latency bound; overlaps misc)
        if (idx >= necnt) return;
        int i = idx * WG + threadIdx.x;
        if (i < e) rank[i] = atomicAdd(&deg[dst[i]], 1);
        return;
    }
    if (idx >= nmisc) return;
    if (idx < 64) {  // Wgt[n*128+k] = Wg[k*128+n]
        int i = idx * WG + threadIdx.x;
        int k = i & 127, nI = i >> 7;
        Wgt[i] = (f16)Wg[(size_t)k * 128 + nI];
    } else if (idx < 192) {  // W1t[n*256+k] = W1[k*128+n]
        int i = (idx - 64) * WG + threadIdx.x;
        int k = i & 255, nI = i >> 8;
        W1t[i] = (f16)W1[(size_t)k * 128 + nI];
    } else {
        int i = (idx - 192) * WG + threadIdx.x;
        if (i < n4) {
            int4 v = ((const int4*)pairs)[i];
            ((float4*)outp)[i] = make_float4((float)v.x, (float)v.y, (float)v.z, (float)v.w);
        }
    }
}

// ============ generic scan1: block-local exclusive scan (+optional dinv) ============
__global__ __launch_bounds__(WG) void k_scan1(const int* __restrict__ deg,
                                              float* __restrict__ dinv,
                                              int* __restrict__ base,
                                              int* __restrict__ bsum, int n) {
    __shared__ int t[WG];
    int tid = threadIdx.x;
    int i = blockIdx.x * WG + tid;
    int v = (i < n) ? deg[i] : 0;
    if (dinv && i < n) dinv[i] = rsqrtf((float)(v + 1));
    t[tid] = v;
    __syncthreads();
    for (int o = 1; o < WG; o <<= 1) {
        int add = (tid >= o) ? t[tid - o] : 0;
        __syncthreads();
        t[tid] += add;
        __syncthreads();
    }
    if (i < n) base[i] = t[tid] - v;  // block-local exclusive
    if (tid == WG - 1) bsum[blockIdx.x] = t[WG - 1];
}

// ============ fused B: edge scan23 || mm_hpk ============
__global__ __launch_bounds__(WG) void k_fusedB(int* __restrict__ base,
                                               const int* __restrict__ bsum,
                                               int n, int total, int nb,
                                               const float* __restrict__ A,
                                               const f16* __restrict__ Wt,
                                               const float* __restrict__ dinv,
                                               __half2* __restrict__ Out, int nmm) {
    __shared__ __align__(16) char smem[64 * 136 * 2 + 128 * 136 * 2];
    int b = blockIdx.x, role = b & 1, idx = b >> 1;
    int tid = threadIdx.x;
    if (role == 0) {  // scan23 for edge base
        if (idx >= nb) return;
        int* t = (int*)smem;
        int v = (tid < nb) ? bsum[tid] : 0;
        t[tid] = v;
        __syncthreads();
        for (int o = 1; o < WG; o <<= 1) {
            int add = (tid >= o) ? t[tid - o] : 0;
            __syncthreads();
            t[tid] += add;
            __syncthreads();
        }
        int off = t[idx] - ((idx < nb) ? bsum[idx] : 0);
        int i = idx * WG + tid;
        if (i < n) {
            base[i] += off;
            if (i == n - 1) base[n] = total;
        }
        return;
    }
    // mm_hpk: Hpk'[r][c] = half2 of (A@W)[r][{c,c+64}] * dinv[r]
    if (idx >= nmm) return;
    f16(*As)[136] = (f16(*)[136])smem;
    f16(*Bs)[136] = (f16(*)[136])(smem + 64 * 136 * 2);
    const int row0 = idx * 64;
    for (int f = tid; f < 128 * 16; f += WG) {
        int r = f >> 4, c = f & 15;
        *(float4*)&Bs[r][c * 8] = ((const float4*)Wt)[r * 16 + c];
    }
    for (int f = tid; f < 64 * 32; f += WG) {
        int r = f >> 5, c = f & 31;
        float4 v = make_float4(0.f, 0.f, 0.f, 0.f);
        if (row0 + r < n) v = ((const float4*)A)[(size_t)(row0 + r) * 32 + c];
        *(f16x4*)&As[r][c * 4] = (f16x4){(f16)v.x, (f16)v.y, (f16)v.z, (f16)v.w};
    }
    __syncthreads();
    const int wv = tid >> 6, lane = tid & 63, m = lane & 15, quad = lane >> 4;
    f32x4 acc[8];
#pragma unroll
    for (int t = 0; t < 8; ++t) acc[t] = (f32x4){0.f, 0.f, 0.f, 0.f};
#pragma unroll
    for (int kk = 0; kk < 4; ++kk) {
        f16x8 af = *(f16x8*)&As[wv * 16 + m][kk * 32 + quad * 8];
#pragma unroll
        for (int t = 0; t < 8; ++t) {
            f16x8 bf = *(f16x8*)&Bs[t * 16 + m][kk * 32 + quad * 8];
            acc[t] = __builtin_amdgcn_mfma_f32_16x16x32_f16(af, bf, acc[t], 0, 0, 0);
        }
    }
#pragma unroll
    for (int r = 0; r < 4; ++r) {
        int row = row0 + wv * 16 + quad * 4 + r;
        if (row < n) {
            float dv = dinv[row];
#pragma unroll
            for (int t = 0; t < 4; ++t)
                Out[(size_t)row * 64 + t * 16 + m] =
                    __floats2half2_rn(acc[t][r] * dv, acc[t + 4][r] * dv);
        }
    }
}

// ============ edge fill: slot precomputed by rank ============
__global__ __launch_bounds__(WG) void k_fill(const int* __restrict__ src,
                                             const int* __restrict__ dst,
                                             const int* __restrict__ base,
                                             const int* __restrict__ rank,
                                             int* __restrict__ esrc, int e) {
    int i = blockIdx.x * WG + threadIdx.x;
    if (i >= e) return;
    esrc[base[dst[i]] + rank[i]] = src[i];
}

// ============ fused C: gather || pair histogram ============
__global__ __launch_bounds__(WG) void k_fusedC(const __half2* __restrict__ Hpk,
                                               const float* __restrict__ dinv,
                                               const float* __restrict__ bg,
                                               const int* __restrict__ base,
                                               const int* __restrict__ esrc,
                                               float* __restrict__ outh, int n,
                                               const int* __restrict__ pairs,
                                               int* __restrict__ pdeg,
                                               int* __restrict__ prank, int p,
                                               int ngath, int npcnt) {
    int tid = threadIdx.x;
    int b = blockIdx.x, role = b & 1, idx = b >> 1;
    if (role == 1) {  // pair histogram (atomic-latency bound; overlaps gather)
        if (idx >= npcnt) return;
        int i = idx * WG + tid;
        if (i < p) prank[i] = atomicAdd(&pdeg[pairs[2 * i]], 1);
        return;
    }
    if (idx >= ngath) return;
    int node = idx * 16 + (tid >> 4);
    int sub = tid & 15;
    if (node >= n) return;
    int4 hh = *(const int4*)(Hpk + (size_t)node * 64 + 4 * sub);
    const int* hp = (const int*)&hh;
    float accl[4], acch[4];
#pragma unroll
    for (int k = 0; k < 4; ++k) {
        hv2 h = __builtin_bit_cast(hv2, hp[k]);
        accl[k] = (float)h[0];
        acch[k] = (float)h[1];
    }
    int j = base[node], jend = base[node + 1];
    for (; j + 4 <= jend; j += 4) {
        int s0 = esrc[j], s1 = esrc[j + 1], s2i = esrc[j + 2], s3 = esrc[j + 3];
        int4 r0 = *(const int4*)(Hpk + (size_t)s0 * 64 + 4 * sub);
        int4 r1 = *(const int4*)(Hpk + (size_t)s1 * 64 + 4 * sub);
        int4 r2 = *(const int4*)(Hpk + (size_t)s2i * 64 + 4 * sub);
        int4 r3 = *(const int4*)(Hpk + (size_t)s3 * 64 + 4 * sub);
        const int* p0 = (const int*)&r0;
        const int* p1 = (const int*)&r1;
        const int* p2 = (const int*)&r2;
        const int* p3 = (const int*)&r3;
#pragma unroll
        for (int k = 0; k < 4; ++k) {
            hv2 h0 = __builtin_bit_cast(hv2, p0[k]);
            hv2 h1 = __builtin_bit_cast(hv2, p1[k]);
            hv2 h2 = __builtin_bit_cast(hv2, p2[k]);
            hv2 h3 = __builtin_bit_cast(hv2, p3[k]);
            accl[k] += (float)h0[0] + (float)h1[0] + (float)h2[0] + (float)h3[0];
            acch[k] += (float)h0[1] + (float)h1[1] + (float)h2[1] + (float)h3[1];
        }
    }
    for (; j < jend; ++j) {
        int s = esrc[j];
        int4 r = *(const int4*)(Hpk + (size_t)s * 64 + 4 * sub);
        const int* pr = (const int*)&r;
#pragma unroll
        for (int k = 0; k < 4; ++k) {
            hv2 h = __builtin_bit_cast(hv2, pr[k]);
            accl[k] += (float)h[0];
            acch[k] += (float)h[1];
        }
    }
    float dv = dinv[node];
    float4 blo = *(const float4*)(bg + 4 * sub);
    float4 bhi = *(const float4*)(bg + 4 * sub + 64);
    *(float4*)&outh[(size_t)node * 128 + 4 * sub] =
        make_float4(fmaf(accl[0], dv, blo.x), fmaf(accl[1], dv, blo.y),
                    fmaf(accl[2], dv, blo.z), fmaf(accl[3], dv, blo.w));
    *(float4*)&outh[(size_t)node * 128 + 64 + 4 * sub] =
        make_float4(fmaf(acch[0], dv, bhi.x), fmaf(acch[1], dv, bhi.y),
                    fmaf(acch[2], dv, bhi.z), fmaf(acch[3], dv, bhi.w));
}

// ============ fused D: pair scan23 || mm_uv ============
__global__ __launch_bounds__(WG) void k_fusedD(int* __restrict__ pbase,
                                               const int* __restrict__ pbsum,
                                               int n, int total, int nb,
                                               const float* __restrict__ A,
                                               const f16* __restrict__ W1t,
                                               const float* __restrict__ b1,
                                               __half2* __restrict__ Up,
                                               __half2* __restrict__ Vp, int nmm) {
    __shared__ __align__(16) char smem[64 * 136 * 2 + 128 * 136 * 2];
    int b = blockIdx.x, role = b & 1, idx = b >> 1;
    int tid = threadIdx.x;
    if (role == 0) {  // scan23 for pair base
        if (idx >= nb) return;
        int* t = (int*)smem;
        int v = (tid < nb) ? pbsum[tid] : 0;
        t[tid] = v;
        __syncthreads();
        for (int o = 1; o < WG; o <<= 1) {
            int add = (tid >= o) ? t[tid - o] : 0;
            __syncthreads();
            t[tid] += add;
            __syncthreads();
        }
        int off = t[idx] - ((idx < nb) ? pbsum[idx] : 0);
        int i = idx * WG + tid;
        if (i < n) {
            pbase[i] += off;
            if (i == n - 1) pbase[n] = total;
        }
        return;
    }
    // mm_uv: U = A@W1a + b1, V = A@W1b; packed (c, c+64)
    if (idx >= nmm) return;
    f16(*As)[136] = (f16(*)[136])smem;
    f16(*Bs)[136] = (f16(*)[136])(smem + 64 * 136 * 2);
    const int row0 = idx * 64;
    for (int f = tid; f < 64 * 32; f += WG) {
        int r = f >> 5, c = f & 31;
        float4 v = make_float4(0.f, 0.f, 0.f, 0.f);
        if (row0 + r < n) v = ((const float4*)A)[(size_t)(row0 + r) * 32 + c];
        *(f16x4*)&As[r][c * 4] = (f16x4){(f16)v.x, (f16)v.y, (f16)v.z, (f16)v.w};
    }
    const int wv = tid >> 6, lane = tid & 63, m = lane & 15, quad = lane >> 4;
    f32x4 acc[8];
#pragma unroll
    for (int ph = 0; ph < 2; ++ph) {
        if (ph) __syncthreads();
        for (int f = tid; f < 128 * 16; f += WG) {
            int r = f >> 4, c = f & 15;
            *(float4*)&Bs[r][c * 8] = *(const float4*)(W1t + (size_t)r * 256 + ph * 128 + c * 8);
        }
        __syncthreads();
#pragma unroll
        for (int t = 0; t < 8; ++t) acc[t] = (f32x4){0.f, 0.f, 0.f, 0.f};
#pragma unroll
        for (int kk = 0; kk < 4; ++kk) {
            f16x8 af = *(f16x8*)&As[wv * 16 + m][kk * 32 + quad * 8];
#pragma unroll
            for (int t = 0; t < 8; ++t) {
                f16x8 bf = *(f16x8*)&Bs[t * 16 + m][kk * 32 + quad * 8];
                acc[t] = __builtin_amdgcn_mfma_f32_16x16x32_f16(af, bf, acc[t], 0, 0, 0);
            }
        }
        __half2* Out = ph ? Vp : Up;
#pragma unroll
        for (int t = 0; t < 4; ++t) {
            float bl = 0.f, bh = 0.f;
            if (!ph) { bl = b1[t * 16 + m]; bh = b1[t * 16 + m + 64]; }
#pragma unroll
            for (int r = 0; r < 4; ++r) {
                int row = row0 + wv * 16 + quad * 4 + r;
                if (row < n)
                    Out[(size_t)row * 64 + t * 16 + m] =
                        __floats2half2_rn(acc[t][r] + bl, acc[t + 4][r] + bh);
            }
        }
    }
}

// ============ pair fill: plist[pbase[a]+prank] = (b, orig idx) ============
__global__ __launch_bounds__(WG) void k_pfill(const int* __restrict__ pairs,
                                              const int* __restrict__ pbase,
                                              const int* __restrict__ prank,
                                              int2* __restrict__ plist, int p) {
    int j = blockIdx.x * WG + threadIdx.x;
    if (j >= p) return;
    int a = pairs[2 * j], bb = pairs[2 * j + 1];
    plist[pbase[a] + prank[j]] = make_int2(bb, j);
}

// --------- node-centric pair MLP over CSR-by-a: 16-lane group per node a.
__global__ __launch_bounds__(WG) void k_pairs_csr(const __half2* __restrict__ U,
                                                  const __half2* __restrict__ V,
                                                  const float* __restrict__ W2,
                                                  const float* __restrict__ b2,
                                                  const int* __restrict__ pbase,
                                                  const int2* __restrict__ plist,
                                                  float* __restrict__ out_logit, int n) {
    int tid = threadIdx.x;
    int node = blockIdx.x * 16 + (tid >> 4);
    int sub = tid & 15;
    if (node >= n) return;
    int j = pbase[node], jend = pbase[node + 1];
    if (j >= jend) return;

    int4 uu = *(const int4*)(U + (size_t)node * 64 + 4 * sub);
    const int* ui = (const int*)&uu;

    float4 w2lo = ((const float4*)W2)[sub];
    float4 w2hi = ((const float4*)(W2 + 64))[sub];
    hv2 w2h[4];
    w2h[0] = hv2{(f16)w2lo.x, (f16)w2hi.x};
    w2h[1] = hv2{(f16)w2lo.y, (f16)w2hi.y};
    w2h[2] = hv2{(f16)w2lo.z, (f16)w2hi.z};
    w2h[3] = hv2{(f16)w2lo.w, (f16)w2hi.w};
    float bb = b2[0];
    const hv2 z2 = hv2{(f16)0.f, (f16)0.f};

    for (; j + 4 <= jend; j += 4) {
        int2 e0 = plist[j], e1 = plist[j + 1], e2 = plist[j + 2], e3 = plist[j + 3];
        int4 v0 = *(const int4*)(V + (size_t)e0.x * 64 + 4 * sub);
        int4 v1 = *(const int4*)(V + (size_t)e1.x * 64 + 4 * sub);
        int4 v2 = *(const int4*)(V + (size_t)e2.x * 64 + 4 * sub);
        int4 v3 = *(const int4*)(V + (size_t)e3.x * 64 + 4 * sub);
        const int* vi0 = (const int*)&v0;
        const int* vi1 = (const int*)&v1;
        const int* vi2 = (const int*)&v2;
        const int* vi3 = (const int*)&v3;
        float p0 = 0.f, p1 = 0.f, p2 = 0.f, p3 = 0.f;
#pragma unroll
        for (int k = 0; k < 4; ++k) {
            hv2 uk = __builtin_bit_cast(hv2, ui[k]);
            hv2 s0 = uk + __builtin_bit_cast(hv2, vi0[k]);
            hv2 s1 = uk + __builtin_bit_cast(hv2, vi1[k]);
            hv2 s2 = uk + __builtin_bit_cast(hv2, vi2[k]);
            hv2 s3 = uk + __builtin_bit_cast(hv2, vi3[k]);
            p0 = __builtin_amdgcn_fdot2(__builtin_elementwise_max(s0, z2), w2h[k], p0, false);
            p1 = __builtin_amdgcn_fdot2(__builtin_elementwise_max(s1, z2), w2h[k], p1, false);
            p2 = __builtin_amdgcn_fdot2(__builtin_elementwise_max(s2, z2), w2h[k], p2, false);
            p3 = __builtin_amdgcn_fdot2(__builtin_elementwise_max(s3, z2), w2h[k], p3, false);
        }
#pragma unroll
        for (int m = 1; m < 16; m <<= 1) {
            p0 += __shfl_xor(p0, m, 64);
            p1 += __shfl_xor(p1, m, 64);
            p2 += __shfl_xor(p2, m, 64);
            p3 += __shfl_xor(p3, m, 64);
        }
        if (sub == 0) {
            out_logit[e0.y] = p0 + bb;
            out_logit[e1.y] = p1 + bb;
            out_logit[e2.y] = p2 + bb;
            out_logit[e3.y] = p3 + bb;
        }
    }
    for (; j < jend; ++j) {
        int2 e0 = plist[j];
        int4 v0 = *(const int4*)(V + (size_t)e0.x * 64 + 4 * sub);
        const int* vi0 = (const int*)&v0;
        float p0 = 0.f;
#pragma unroll
        for (int k = 0; k < 4; ++k) {
            hv2 s0 = __builtin_bit_cast(hv2, ui[k]) + __builtin_bit_cast(hv2, vi0[k]);
            p0 = __builtin_amdgcn_fdot2(__builtin_elementwise_max(s0, z2), w2h[k], p0, false);
        }
#pragma unroll
        for (int m = 1; m < 16; m <<= 1) p0 += __shfl_xor(p0, m, 64);
        if (sub == 0) out_logit[e0.y] = p0 + bb;
    }
}

extern "C" void kernel_launch(void* const* d_in, const int* in_sizes, int n_in,
                              void* d_out, int out_size, void* d_ws, size_t ws_size,
                              hipStream_t stream) {
    const float* x     = (const float*)d_in[0];
    const int*   eidx  = (const int*)d_in[1];
    const int*   pairs = (const int*)d_in[2];
    const float* W_gcn = (const float*)d_in[3];
    const float* b_gcn = (const float*)d_in[4];
    const float* W1    = (const float*)d_in[5];
    const float* b1    = (const float*)d_in[6];
    const float* W2    = (const float*)d_in[7];
    const float* b2    = (const float*)d_in[8];

    const int N = in_sizes[0] / 128;
    const int E = in_sizes[1] / 2;
    const int P = in_sizes[2] / 2;
    const int* esrc_in = eidx;
    const int* edst_in = eidx + E;

    // workspace layout (4-byte units)
    float* ws      = (float*)d_ws;
    int*   deg     = (int*)d_ws;                  // [N]
    int*   pdeg    = (int*)d_ws + N;              // [N] (contiguous with deg: one memset)
    float* dinv    = ws + 131072;                 // [N]
    int*   base    = (int*)(ws + 196608);         // [N+1]
    int*   pbase   = (int*)(ws + 262144);         // [N+1]
    int*   bsum    = (int*)(ws + 327680);         // [256]
    int*   pbsum   = (int*)(ws + 327936);         // [256]
    f16*   Wt_gcn  = (f16*)(ws + 328192);         // [128*128] f16
    f16*   W1t     = (f16*)(ws + 336384);         // [128*256] f16
    int*   rank    = (int*)(ws + 352768);         // [E]
    int*   ecsr    = rank + (size_t)E;            // [E]
    __half2* Hpk   = (__half2*)(ecsr + (size_t)E);  // [N*64]
    __half2* Upk   = Hpk + (size_t)N * 64;        // [N*64]
    __half2* Vpk   = Upk + (size_t)N * 64;        // [N*64]
    int2*  plist   = (int2*)(Vpk + (size_t)N * 64);  // [P] (b, orig_idx)

    float* out_logit = (float*)d_out;             // [P]
    float* out_pairs = out_logit + P;             // [2P] as float
    float* out_h     = out_logit + 3 * (size_t)P; // [N*128]
    // prank aliases out_logit: written by fused_C (step 6), read by k_pfill
    // (step 9), dead once k_pairs_csr (step 10) overwrites every element.
    int*   prank   = (int*)d_out;                 // [P]

    const int nb    = (N + WG - 1) / WG;          // 196
    const int nmm   = (N + 63) / 64;              // 782
    const int ngath = (N + 15) / 16;              // 3125
    const int nmisc = 192 + (P / 2 + WG - 1) / WG;
    const int necnt = (E + WG - 1) / WG;
    const int npcnt = (P + WG - 1) / WG;
    dim3 blk(WG);

    hipMemsetAsync(deg, 0, (size_t)(2 * N) * 4, stream);
    // A: misc || edge histogram (atomics overlap transposes/cvt)
    k_fusedA <<<2 * (nmisc > necnt ? nmisc : necnt), blk, 0, stream>>>(
        W_gcn, Wt_gcn, W1, W1t, pairs, out_pairs, P / 2,
        edst_in, deg, rank, E, nmisc, necnt);
    // edge scan1 (also produces dinv)
    k_scan1  <<<nb, blk, 0, stream>>>(deg, dinv, base, bsum, N);
    // B: edge scan23 || mm_hpk
    k_fusedB <<<2 * (nb > nmm ? nb : nmm), blk, 0, stream>>>(
        base, bsum, N, E, nb, x, Wt_gcn, dinv, Hpk, nmm);
    // edge fill
    k_fill   <<<necnt, blk, 0, stream>>>(esrc_in, edst_in, base, rank, ecsr, E);
    // C: gather || pair histogram (atomics overlap the big random gather)
    k_fusedC <<<2 * (ngath > npcnt ? ngath : npcnt), blk, 0, stream>>>(
        Hpk, dinv, b_gcn, base, ecsr, out_h, N,
        pairs, pdeg, prank, P, ngath, npcnt);
    // pair scan1 (no dinv)
    k_scan1  <<<nb, blk, 0, stream>>>(pdeg, nullptr, pbase, pbsum, N);
    // D: pair scan23 || mm_uv
    k_fusedD <<<2 * (nb > nmm ? nb : nmm), blk, 0, stream>>>(
        pbase, pbsum, N, P, nb, out_h, W1t, b1, Upk, Vpk, nmm);
    // pair fill
    k_pfill  <<<npcnt, blk, 0, stream>>>(pairs, pbase, prank, plist, P);
    // pair MLP over CSR-by-a
    k_pairs_csr <<<ngath, blk, 0, stream>>>(Upk, Vpk, W2, b2, pbase, plist, out_logit, N);
}

// Round 4
// 276.008 us; speedup vs baseline: 1.1675x; 1.1675x over previous
//
#include <hip/hip_runtime.h>
#include <hip/hip_fp16.h>

#define WG 256

typedef _Float16 f16;
typedef _Float16 hv2 __attribute__((ext_vector_type(2)));
typedef _Float16 f16x4 __attribute__((ext_vector_type(4)));
typedef _Float16 f16x8 __attribute__((ext_vector_type(8)));
typedef float f32x4 __attribute__((ext_vector_type(4)));

// ---------- misc0: transpose W_gcn (f16), transpose W1 (f16)
__global__ __launch_bounds__(WG) void k_misc0(const float* __restrict__ Wg,
                                              f16* __restrict__ Wgt,
                                              const float* __restrict__ W1,
                                              f16* __restrict__ W1t) {
    int b = blockIdx.x;
    if (b < 64) {  // Wgt[n*128+k] = Wg[k*128+n]
        int i = b * WG + threadIdx.x;
        int k = i & 127, nI = i >> 7;
        Wgt[i] = (f16)Wg[(size_t)k * 128 + nI];
    } else {  // W1t[n*256+k] = W1[k*128+n]
        int i = (b - 64) * WG + threadIdx.x;
        int k = i & 255, nI = i >> 8;
        W1t[i] = (f16)W1[(size_t)k * 128 + nI];
    }
}

// ============ fused A: mm_hpk (raw h, no dinv) || edge histogram || pair cvt
// slot = b&3: 0 -> GEMM, 1/3 -> histogram (2 slots: biggest stream), 2 -> cvt.
__global__ __launch_bounds__(WG) void k_fusedA(const float* __restrict__ A,
                                               const f16* __restrict__ Wt,
                                               __half2* __restrict__ Out, int n,
                                               const int* __restrict__ dst,
                                               int* __restrict__ deg,
                                               int* __restrict__ rank, int e,
                                               const int* __restrict__ pairs,
                                               float* __restrict__ outp, int n4,
                                               int nmm, int necnt, int ncvt) {
    __shared__ __align__(16) char smem[64 * 136 * 2 + 128 * 136 * 2];
    int b = blockIdx.x, slot = b & 3, idx = b >> 2;
    int tid = threadIdx.x;
    if (slot == 1 || slot == 3) {  // edge histogram: atomic-fabric bound
        int hid = idx * 2 + (slot >> 1);
        if (hid >= necnt) return;
        int i = hid * WG + tid;
        if (i < e) rank[i] = atomicAdd(&deg[dst[i]], 1);
        return;
    }
    if (slot == 2) {  // pair int->float cvt (streaming)
        if (idx >= ncvt) return;
        int i = idx * WG + tid;
        if (i < n4) {
            int4 v = ((const int4*)pairs)[i];
            ((float4*)outp)[i] = make_float4((float)v.x, (float)v.y, (float)v.z, (float)v.w);
        }
        return;
    }
    // slot 0: Hpk'[r][c] = half2 of (A@W)[r][{c,c+64}]   (raw, dinv folded into gather)
    if (idx >= nmm) return;
    f16(*As)[136] = (f16(*)[136])smem;
    f16(*Bs)[136] = (f16(*)[136])(smem + 64 * 136 * 2);
    const int row0 = idx * 64;
    for (int f = tid; f < 128 * 16; f += WG) {
        int r = f >> 4, c = f & 15;
        *(float4*)&Bs[r][c * 8] = ((const float4*)Wt)[r * 16 + c];
    }
    for (int f = tid; f < 64 * 32; f += WG) {
        int r = f >> 5, c = f & 31;
        float4 v = make_float4(0.f, 0.f, 0.f, 0.f);
        if (row0 + r < n) v = ((const float4*)A)[(size_t)(row0 + r) * 32 + c];
        *(f16x4*)&As[r][c * 4] = (f16x4){(f16)v.x, (f16)v.y, (f16)v.z, (f16)v.w};
    }
    __syncthreads();
    const int wv = tid >> 6, lane = tid & 63, m = lane & 15, quad = lane >> 4;
    f32x4 acc[8];
#pragma unroll
    for (int t = 0; t < 8; ++t) acc[t] = (f32x4){0.f, 0.f, 0.f, 0.f};
#pragma unroll
    for (int kk = 0; kk < 4; ++kk) {
        f16x8 af = *(f16x8*)&As[wv * 16 + m][kk * 32 + quad * 8];
#pragma unroll
        for (int t = 0; t < 8; ++t) {
            f16x8 bf = *(f16x8*)&Bs[t * 16 + m][kk * 32 + quad * 8];
            acc[t] = __builtin_amdgcn_mfma_f32_16x16x32_f16(af, bf, acc[t], 0, 0, 0);
        }
    }
#pragma unroll
    for (int r = 0; r < 4; ++r) {
        int row = row0 + wv * 16 + quad * 4 + r;
        if (row < n) {
#pragma unroll
            for (int t = 0; t < 4; ++t)
                Out[(size_t)row * 64 + t * 16 + m] =
                    __floats2half2_rn(acc[t][r], acc[t + 4][r]);
        }
    }
}

// ============ scan1: block-local exclusive scan + dinv ============
__global__ __launch_bounds__(WG) void k_scan1(const int* __restrict__ deg,
                                              float* __restrict__ dinv,
                                              int* __restrict__ base,
                                              int* __restrict__ bsum, int n) {
    __shared__ int t[WG];
    int tid = threadIdx.x;
    int i = blockIdx.x * WG + tid;
    int v = (i < n) ? deg[i] : 0;
    if (i < n) dinv[i] = rsqrtf((float)(v + 1));
    t[tid] = v;
    __syncthreads();
    for (int o = 1; o < WG; o <<= 1) {
        int add = (tid >= o) ? t[tid - o] : 0;
        __syncthreads();
        t[tid] += add;
        __syncthreads();
    }
    if (i < n) base[i] = t[tid] - v;  // block-local exclusive
    if (tid == WG - 1) bsum[blockIdx.x] = t[WG - 1];
}

// fused scan2+scan3: each block scans bsum in LDS, adds its own prefix.
__global__ __launch_bounds__(WG) void k_scan23(int* __restrict__ base,
                                               const int* __restrict__ bsum,
                                               int n, int e, int nb) {
    __shared__ int t[WG];
    int tid = threadIdx.x;
    int v = (tid < nb) ? bsum[tid] : 0;
    t[tid] = v;
    __syncthreads();
    for (int o = 1; o < WG; o <<= 1) {
        int add = (tid >= o) ? t[tid - o] : 0;
        __syncthreads();
        t[tid] += add;
        __syncthreads();
    }
    int off = t[blockIdx.x] - ((blockIdx.x < nb) ? bsum[blockIdx.x] : 0);
    int i = blockIdx.x * WG + tid;
    if (i < n) {
        base[i] += off;
        if (i == n - 1) base[n] = e;
    }
}

// ---------------- fill: no atomics — slot precomputed by rank
__global__ __launch_bounds__(WG) void k_fill(const int* __restrict__ src,
                                             const int* __restrict__ dst,
                                             const int* __restrict__ base,
                                             const int* __restrict__ rank,
                                             int* __restrict__ esrc, int e) {
    int i = blockIdx.x * WG + threadIdx.x;
    if (i >= e) return;
    esrc[base[dst[i]] + rank[i]] = src[i];
}

// ------------- gather: out_h[d] = (h[d]*dinv[d] + sum_in h[s]*dinv[s]) * dinv[d] + b
// Hpk holds RAW h (packed c,c+64); dinv[src] folded in via fma.
__global__ __launch_bounds__(WG) void k_gather(const __half2* __restrict__ Hpk,
                                               const float* __restrict__ dinv,
                                               const float* __restrict__ bg,
                                               const int* __restrict__ base,
                                               const int* __restrict__ esrc,
                                               float* __restrict__ outh, int n) {
    int tid = threadIdx.x;
    int node = blockIdx.x * 16 + (tid >> 4);
    int sub = tid & 15;
    if (node >= n) return;
    float dv = dinv[node];
    int4 hh = *(const int4*)(Hpk + (size_t)node * 64 + 4 * sub);
    const int* hp = (const int*)&hh;
    float accl[4], acch[4];
#pragma unroll
    for (int k = 0; k < 4; ++k) {
        hv2 h = __builtin_bit_cast(hv2, hp[k]);
        accl[k] = (float)h[0] * dv;
        acch[k] = (float)h[1] * dv;
    }
    int j = base[node], jend = base[node + 1];
    for (; j + 4 <= jend; j += 4) {
        int s0 = esrc[j], s1 = esrc[j + 1], s2i = esrc[j + 2], s3 = esrc[j + 3];
        float ds0 = dinv[s0], ds1 = dinv[s1], ds2 = dinv[s2i], ds3 = dinv[s3];
        int4 r0 = *(const int4*)(Hpk + (size_t)s0 * 64 + 4 * sub);
        int4 r1 = *(const int4*)(Hpk + (size_t)s1 * 64 + 4 * sub);
        int4 r2 = *(const int4*)(Hpk + (size_t)s2i * 64 + 4 * sub);
        int4 r3 = *(const int4*)(Hpk + (size_t)s3 * 64 + 4 * sub);
        const int* p0 = (const int*)&r0;
        const int* p1 = (const int*)&r1;
        const int* p2 = (const int*)&r2;
        const int* p3 = (const int*)&r3;
#pragma unroll
        for (int k = 0; k < 4; ++k) {
            hv2 h0 = __builtin_bit_cast(hv2, p0[k]);
            hv2 h1 = __builtin_bit_cast(hv2, p1[k]);
            hv2 h2 = __builtin_bit_cast(hv2, p2[k]);
            hv2 h3 = __builtin_bit_cast(hv2, p3[k]);
            accl[k] = fmaf((float)h0[0], ds0, accl[k]);
            accl[k] = fmaf((float)h1[0], ds1, accl[k]);
            accl[k] = fmaf((float)h2[0], ds2, accl[k]);
            accl[k] = fmaf((float)h3[0], ds3, accl[k]);
            acch[k] = fmaf((float)h0[1], ds0, acch[k]);
            acch[k] = fmaf((float)h1[1], ds1, acch[k]);
            acch[k] = fmaf((float)h2[1], ds2, acch[k]);
            acch[k] = fmaf((float)h3[1], ds3, acch[k]);
        }
    }
    for (; j < jend; ++j) {
        int s = esrc[j];
        float ds = dinv[s];
        int4 r = *(const int4*)(Hpk + (size_t)s * 64 + 4 * sub);
        const int* pr = (const int*)&r;
#pragma unroll
        for (int k = 0; k < 4; ++k) {
            hv2 h = __builtin_bit_cast(hv2, pr[k]);
            accl[k] = fmaf((float)h[0], ds, accl[k]);
            acch[k] = fmaf((float)h[1], ds, acch[k]);
        }
    }
    float4 blo = *(const float4*)(bg + 4 * sub);
    float4 bhi = *(const float4*)(bg + 4 * sub + 64);
    *(float4*)&outh[(size_t)node * 128 + 4 * sub] =
        make_float4(fmaf(accl[0], dv, blo.x), fmaf(accl[1], dv, blo.y),
                    fmaf(accl[2], dv, blo.z), fmaf(accl[3], dv, blo.w));
    *(float4*)&outh[(size_t)node * 128 + 64 + 4 * sub] =
        make_float4(fmaf(acch[0], dv, bhi.x), fmaf(acch[1], dv, bhi.y),
                    fmaf(acch[2], dv, bhi.z), fmaf(acch[3], dv, bhi.w));
}

// ---------- Fused U/V MFMA GEMM: U = A@W1a + b1, V = A@W1b; packed (c, c+64)
__global__ __launch_bounds__(WG) void k_mm_uv(const float* __restrict__ A,
                                              const f16* __restrict__ W1t,
                                              const float* __restrict__ b1,
                                              __half2* __restrict__ Up,
                                              __half2* __restrict__ Vp, int n) {
    __shared__ f16 As[64][136];
    __shared__ f16 Bs[128][136];
    const int tid = threadIdx.x;
    const int row0 = blockIdx.x * 64;
    for (int f = tid; f < 64 * 32; f += WG) {
        int r = f >> 5, c = f & 31;
        float4 v = make_float4(0.f, 0.f, 0.f, 0.f);
        if (row0 + r < n) v = ((const float4*)A)[(size_t)(row0 + r) * 32 + c];
        *(f16x4*)&As[r][c * 4] = (f16x4){(f16)v.x, (f16)v.y, (f16)v.z, (f16)v.w};
    }
    const int wv = tid >> 6, lane = tid & 63, m = lane & 15, quad = lane >> 4;
    f32x4 acc[8];
#pragma unroll
    for (int ph = 0; ph < 2; ++ph) {
        if (ph) __syncthreads();
        for (int f = tid; f < 128 * 16; f += WG) {
            int r = f >> 4, c = f & 15;
            *(float4*)&Bs[r][c * 8] = *(const float4*)(W1t + (size_t)r * 256 + ph * 128 + c * 8);
        }
        __syncthreads();
#pragma unroll
        for (int t = 0; t < 8; ++t) acc[t] = (f32x4){0.f, 0.f, 0.f, 0.f};
#pragma unroll
        for (int kk = 0; kk < 4; ++kk) {
            f16x8 af = *(f16x8*)&As[wv * 16 + m][kk * 32 + quad * 8];
#pragma unroll
            for (int t = 0; t < 8; ++t) {
                f16x8 bf = *(f16x8*)&Bs[t * 16 + m][kk * 32 + quad * 8];
                acc[t] = __builtin_amdgcn_mfma_f32_16x16x32_f16(af, bf, acc[t], 0, 0, 0);
            }
        }
        __half2* Out = ph ? Vp : Up;
#pragma unroll
        for (int t = 0; t < 4; ++t) {
            float bl = 0.f, bh = 0.f;
            if (!ph) { bl = b1[t * 16 + m]; bh = b1[t * 16 + m + 64]; }
#pragma unroll
            for (int r = 0; r < 4; ++r) {
                int row = row0 + wv * 16 + quad * 4 + r;
                if (row < n)
                    Out[(size_t)row * 64 + t * 16 + m] =
                        __floats2half2_rn(acc[t][r] + bl, acc[t + 4][r] + bh);
            }
        }
    }
}

// --------- 4 pairs per 16-lane group (16/wave): logit = relu(U[a]+V[b]).W2 + b2
__global__ __launch_bounds__(WG) void k_pair16(const __half2* __restrict__ U,
                                               const __half2* __restrict__ V,
                                               const float* __restrict__ W2,
                                               const float* __restrict__ b2,
                                               const int* __restrict__ pairs,
                                               float* __restrict__ out_logit, int p) {
    int wv = (blockIdx.x * WG + threadIdx.x) >> 6;
    int lane = threadIdx.x & 63;
    int g = lane >> 4, sub = lane & 15;
    int qb = wv * 16 + g;  // this group: pairs qb, qb+4, qb+8, qb+12
    if (qb >= p) return;
    int q0 = qb;
    int q1 = (qb + 4 < p) ? qb + 4 : qb;
    int q2 = (qb + 8 < p) ? qb + 8 : qb;
    int q3 = (qb + 12 < p) ? qb + 12 : qb;
    int a0 = pairs[2 * q0], b0 = pairs[2 * q0 + 1];
    int a1 = pairs[2 * q1], b1i = pairs[2 * q1 + 1];
    int a2 = pairs[2 * q2], b2i = pairs[2 * q2 + 1];
    int a3 = pairs[2 * q3], b3i = pairs[2 * q3 + 1];

    // issue all 8 gather loads before any use
    int4 u0 = *(const int4*)(U + (size_t)a0 * 64 + 4 * sub);
    int4 v0 = *(const int4*)(V + (size_t)b0 * 64 + 4 * sub);
    int4 u1 = *(const int4*)(U + (size_t)a1 * 64 + 4 * sub);
    int4 v1 = *(const int4*)(V + (size_t)b1i * 64 + 4 * sub);
    int4 u2 = *(const int4*)(U + (size_t)a2 * 64 + 4 * sub);
    int4 v2 = *(const int4*)(V + (size_t)b2i * 64 + 4 * sub);
    int4 u3 = *(const int4*)(U + (size_t)a3 * 64 + 4 * sub);
    int4 v3 = *(const int4*)(V + (size_t)b3i * 64 + 4 * sub);

    float4 w2lo = ((const float4*)W2)[sub];
    float4 w2hi = ((const float4*)(W2 + 64))[sub];
    hv2 w2h[4];
    w2h[0] = hv2{(f16)w2lo.x, (f16)w2hi.x};
    w2h[1] = hv2{(f16)w2lo.y, (f16)w2hi.y};
    w2h[2] = hv2{(f16)w2lo.z, (f16)w2hi.z};
    w2h[3] = hv2{(f16)w2lo.w, (f16)w2hi.w};

    const int* ui0 = (const int*)&u0;
    const int* vi0 = (const int*)&v0;
    const int* ui1 = (const int*)&u1;
    const int* vi1 = (const int*)&v1;
    const int* ui2 = (const int*)&u2;
    const int* vi2 = (const int*)&v2;
    const int* ui3 = (const int*)&u3;
    const int* vi3 = (const int*)&v3;

    const hv2 z2 = hv2{(f16)0.f, (f16)0.f};
    float p0 = 0.f, p1 = 0.f, p2 = 0.f, p3 = 0.f;
#pragma unroll
    for (int k = 0; k < 4; ++k) {
        hv2 s0 = __builtin_bit_cast(hv2, ui0[k]) + __builtin_bit_cast(hv2, vi0[k]);
        hv2 s1 = __builtin_bit_cast(hv2, ui1[k]) + __builtin_bit_cast(hv2, vi1[k]);
        hv2 s2 = __builtin_bit_cast(hv2, ui2[k]) + __builtin_bit_cast(hv2, vi2[k]);
        hv2 s3 = __builtin_bit_cast(hv2, ui3[k]) + __builtin_bit_cast(hv2, vi3[k]);
        p0 = __builtin_amdgcn_fdot2(__builtin_elementwise_max(s0, z2), w2h[k], p0, false);
        p1 = __builtin_amdgcn_fdot2(__builtin_elementwise_max(s1, z2), w2h[k], p1, false);
        p2 = __builtin_amdgcn_fdot2(__builtin_elementwise_max(s2, z2), w2h[k], p2, false);
        p3 = __builtin_amdgcn_fdot2(__builtin_elementwise_max(s3, z2), w2h[k], p3, false);
    }
#pragma unroll
    for (int m = 1; m < 16; m <<= 1) {
        p0 += __shfl_xor(p0, m, 64);
        p1 += __shfl_xor(p1, m, 64);
        p2 += __shfl_xor(p2, m, 64);
        p3 += __shfl_xor(p3, m, 64);
    }
    if (sub == 0) {
        float bb = b2[0];
        out_logit[q0] = p0 + bb;
        if (qb + 4 < p) out_logit[qb + 4] = p1 + bb;
        if (qb + 8 < p) out_logit[qb + 8] = p2 + bb;
        if (qb + 12 < p) out_logit[qb + 12] = p3 + bb;
    }
}

extern "C" void kernel_launch(void* const* d_in, const int* in_sizes, int n_in,
                              void* d_out, int out_size, void* d_ws, size_t ws_size,
                              hipStream_t stream) {
    const float* x     = (const float*)d_in[0];
    const int*   eidx  = (const int*)d_in[1];
    const int*   pairs = (const int*)d_in[2];
    const float* W_gcn = (const float*)d_in[3];
    const float* b_gcn = (const float*)d_in[4];
    const float* W1    = (const float*)d_in[5];
    const float* b1    = (const float*)d_in[6];
    const float* W2    = (const float*)d_in[7];
    const float* b2    = (const float*)d_in[8];

    const int N = in_sizes[0] / 128;
    const int E = in_sizes[1] / 2;
    const int P = in_sizes[2] / 2;
    const int* esrc_in = eidx;
    const int* edst_in = eidx + E;

    // workspace layout (4-byte units) — same as R1 (known-good)
    float* ws      = (float*)d_ws;
    int*   deg     = (int*)d_ws;                  // [N]
    float* dinv    = ws + 65536;                  // [N]
    int*   base    = (int*)(ws + 131072);         // [N+1]
    int*   bsum    = (int*)(ws + 196608);         // [256]
    f16*   Wt_gcn  = (f16*)(ws + 197120);         // [128*128] f16
    f16*   W1t     = (f16*)(ws + 205312);         // [128*256] f16
    int*   rank    = (int*)(ws + 221696);         // [E]
    int*   ecsr    = rank + (size_t)E;            // [E]
    __half2* Hpk   = (__half2*)(ecsr + (size_t)E);  // [N*64]  (raw h, packed c,c+64)
    __half2* Upk   = Hpk + (size_t)N * 64;        // [N*64]
    __half2* Vpk   = Upk + (size_t)N * 64;        // [N*64]

    float* out_logit = (float*)d_out;             // [P]
    float* out_pairs = out_logit + P;             // [2P] as float
    float* out_h     = out_logit + 3 * (size_t)P; // [N*128]

    const int nb    = (N + WG - 1) / WG;          // 196
    const int nmm   = (N + 63) / 64;              // 782
    const int necnt = (E + WG - 1) / WG;          // 3125
    const int ncvt  = (P / 2 + WG - 1) / WG;      // 1954
    int gmax = nmm;
    int h2 = (necnt + 1) / 2;
    if (h2 > gmax) gmax = h2;
    if (ncvt > gmax) gmax = ncvt;
    dim3 blk(WG);

    hipMemsetAsync(deg, 0, (size_t)N * 4, stream);
    // transposes (Wgt consumed by fusedA, so must precede it)
    k_misc0  <<<192, blk, 0, stream>>>(W_gcn, Wt_gcn, W1, W1t);
    // A: mm_hpk (raw h) || edge histogram || pair cvt  — hides ~30us of atomics
    k_fusedA <<<4 * gmax, blk, 0, stream>>>(x, Wt_gcn, Hpk, N,
                                            edst_in, deg, rank, E,
                                            pairs, out_pairs, P / 2,
                                            nmm, necnt, ncvt);
    k_scan1  <<<nb, blk, 0, stream>>>(deg, dinv, base, bsum, N);
    k_scan23 <<<nb, blk, 0, stream>>>(base, bsum, N, E, nb);
    k_fill   <<<necnt, blk, 0, stream>>>(esrc_in, edst_in, base, rank, ecsr, E);
    k_gather <<<(N + 15) / 16, blk, 0, stream>>>(Hpk, dinv, b_gcn, base, ecsr, out_h, N);
    k_mm_uv  <<<nmm, blk, 0, stream>>>(out_h, W1t, b1, Upk, Vpk, N);
    k_pair16 <<<(P + 63) / 64, blk, 0, stream>>>(Upk, Vpk, W2, b2, pairs, out_logit, P);
}

// Round 5
// 266.716 us; speedup vs baseline: 1.2081x; 1.0348x over previous
//
#include <hip/hip_runtime.h>
#include <hip/hip_fp16.h>

#define WG 256

typedef _Float16 f16;
typedef _Float16 hv2 __attribute__((ext_vector_type(2)));
typedef _Float16 f16x4 __attribute__((ext_vector_type(4)));
typedef _Float16 f16x8 __attribute__((ext_vector_type(8)));
typedef float f32x4 __attribute__((ext_vector_type(4)));

// ---------- misc0: transpose W_gcn (f16), transpose W1 (f16)
__global__ __launch_bounds__(WG) void k_misc0(const float* __restrict__ Wg,
                                              f16* __restrict__ Wgt,
                                              const float* __restrict__ W1,
                                              f16* __restrict__ W1t) {
    int b = blockIdx.x;
    if (b < 64) {  // Wgt[n*128+k] = Wg[k*128+n]
        int i = b * WG + threadIdx.x;
        int k = i & 127, nI = i >> 7;
        Wgt[i] = (f16)Wg[(size_t)k * 128 + nI];
    } else {  // W1t[n*256+k] = W1[k*128+n]
        int i = (b - 64) * WG + threadIdx.x;
        int k = i & 255, nI = i >> 8;
        W1t[i] = (f16)W1[(size_t)k * 128 + nI];
    }
}

// ============ fused A: mm_hpk (raw h, no dinv) || edge histogram || pair cvt
// slot = b&3: 0 -> GEMM, 1/3 -> histogram (2 slots: biggest stream), 2 -> cvt.
__global__ __launch_bounds__(WG) void k_fusedA(const float* __restrict__ A,
                                               const f16* __restrict__ Wt,
                                               __half2* __restrict__ Out, int n,
                                               const int* __restrict__ dst,
                                               int* __restrict__ deg,
                                               int* __restrict__ rank, int e,
                                               const int* __restrict__ pairs,
                                               float* __restrict__ outp, int n4,
                                               int nmm, int necnt, int ncvt) {
    __shared__ __align__(16) char smem[64 * 136 * 2 + 128 * 136 * 2];
    int b = blockIdx.x, slot = b & 3, idx = b >> 2;
    int tid = threadIdx.x;
    if (slot == 1 || slot == 3) {  // edge histogram: atomic-fabric bound
        int hid = idx * 2 + (slot >> 1);
        if (hid >= necnt) return;
        int i = hid * WG + tid;
        if (i < e) rank[i] = atomicAdd(&deg[dst[i]], 1);
        return;
    }
    if (slot == 2) {  // pair int->float cvt (streaming)
        if (idx >= ncvt) return;
        int i = idx * WG + tid;
        if (i < n4) {
            int4 v = ((const int4*)pairs)[i];
            ((float4*)outp)[i] = make_float4((float)v.x, (float)v.y, (float)v.z, (float)v.w);
        }
        return;
    }
    // slot 0: Hpk'[r][c] = half2 of (A@W)[r][{c,c+64}]   (raw, dinv folded into gather)
    if (idx >= nmm) return;
    f16(*As)[136] = (f16(*)[136])smem;
    f16(*Bs)[136] = (f16(*)[136])(smem + 64 * 136 * 2);
    const int row0 = idx * 64;
    for (int f = tid; f < 128 * 16; f += WG) {
        int r = f >> 4, c = f & 15;
        *(float4*)&Bs[r][c * 8] = ((const float4*)Wt)[r * 16 + c];
    }
    for (int f = tid; f < 64 * 32; f += WG) {
        int r = f >> 5, c = f & 31;
        float4 v = make_float4(0.f, 0.f, 0.f, 0.f);
        if (row0 + r < n) v = ((const float4*)A)[(size_t)(row0 + r) * 32 + c];
        *(f16x4*)&As[r][c * 4] = (f16x4){(f16)v.x, (f16)v.y, (f16)v.z, (f16)v.w};
    }
    __syncthreads();
    const int wv = tid >> 6, lane = tid & 63, m = lane & 15, quad = lane >> 4;
    f32x4 acc[8];
#pragma unroll
    for (int t = 0; t < 8; ++t) acc[t] = (f32x4){0.f, 0.f, 0.f, 0.f};
#pragma unroll
    for (int kk = 0; kk < 4; ++kk) {
        f16x8 af = *(f16x8*)&As[wv * 16 + m][kk * 32 + quad * 8];
#pragma unroll
        for (int t = 0; t < 8; ++t) {
            f16x8 bf = *(f16x8*)&Bs[t * 16 + m][kk * 32 + quad * 8];
            acc[t] = __builtin_amdgcn_mfma_f32_16x16x32_f16(af, bf, acc[t], 0, 0, 0);
        }
    }
#pragma unroll
    for (int r = 0; r < 4; ++r) {
        int row = row0 + wv * 16 + quad * 4 + r;
        if (row < n) {
#pragma unroll
            for (int t = 0; t < 4; ++t)
                Out[(size_t)row * 64 + t * 16 + m] =
                    __floats2half2_rn(acc[t][r], acc[t + 4][r]);
        }
    }
}

// ============ scan1: block-local exclusive scan + dinv ============
__global__ __launch_bounds__(WG) void k_scan1(const int* __restrict__ deg,
                                              float* __restrict__ dinv,
                                              int* __restrict__ base,
                                              int* __restrict__ bsum, int n) {
    __shared__ int t[WG];
    int tid = threadIdx.x;
    int i = blockIdx.x * WG + tid;
    int v = (i < n) ? deg[i] : 0;
    if (i < n) dinv[i] = rsqrtf((float)(v + 1));
    t[tid] = v;
    __syncthreads();
    for (int o = 1; o < WG; o <<= 1) {
        int add = (tid >= o) ? t[tid - o] : 0;
        __syncthreads();
        t[tid] += add;
        __syncthreads();
    }
    if (i < n) base[i] = t[tid] - v;  // block-local exclusive
    if (tid == WG - 1) bsum[blockIdx.x] = t[WG - 1];
}

// fused scan2+scan3: each block scans bsum in LDS, adds its own prefix.
__global__ __launch_bounds__(WG) void k_scan23(int* __restrict__ base,
                                               const int* __restrict__ bsum,
                                               int n, int e, int nb) {
    __shared__ int t[WG];
    int tid = threadIdx.x;
    int v = (tid < nb) ? bsum[tid] : 0;
    t[tid] = v;
    __syncthreads();
    for (int o = 1; o < WG; o <<= 1) {
        int add = (tid >= o) ? t[tid - o] : 0;
        __syncthreads();
        t[tid] += add;
        __syncthreads();
    }
    int off = t[blockIdx.x] - ((blockIdx.x < nb) ? bsum[blockIdx.x] : 0);
    int i = blockIdx.x * WG + tid;
    if (i < n) {
        base[i] += off;
        if (i == n - 1) base[n] = e;
    }
}

// ---------------- fill: no atomics — slot precomputed by rank
__global__ __launch_bounds__(WG) void k_fill(const int* __restrict__ src,
                                             const int* __restrict__ dst,
                                             const int* __restrict__ base,
                                             const int* __restrict__ rank,
                                             int* __restrict__ esrc, int e) {
    int i = blockIdx.x * WG + threadIdx.x;
    if (i >= e) return;
    esrc[base[dst[i]] + rank[i]] = src[i];
}

// ------------- gather: out_h[d] = (h[d]*dinv[d] + sum_in h[s]*dinv[s]) * dinv[d] + b
// Hpk holds RAW h (packed c,c+64); dinv[src] folded in via fma.
// 8-deep row batching: all 8 esrc/dinv/row loads issued before any accumulate
// (pair16-style MLP). Tail = clamped index + ds=0 masked fma (bit-identical).
__global__ __launch_bounds__(WG) void k_gather(const __half2* __restrict__ Hpk,
                                               const float* __restrict__ dinv,
                                               const float* __restrict__ bg,
                                               const int* __restrict__ base,
                                               const int* __restrict__ esrc,
                                               float* __restrict__ outh, int n) {
    int tid = threadIdx.x;
    int node = blockIdx.x * 16 + (tid >> 4);
    int sub = tid & 15;
    if (node >= n) return;
    float dv = dinv[node];
    int4 hh = *(const int4*)(Hpk + (size_t)node * 64 + 4 * sub);
    const int* hp = (const int*)&hh;
    float accl[4], acch[4];
#pragma unroll
    for (int k = 0; k < 4; ++k) {
        hv2 h = __builtin_bit_cast(hv2, hp[k]);
        accl[k] = (float)h[0] * dv;
        acch[k] = (float)h[1] * dv;
    }
    const int j = base[node], jend = base[node + 1];
    for (int j0 = j; j0 < jend; j0 += 8) {
        int s[8];
#pragma unroll
        for (int t = 0; t < 8; ++t) {
            int jt = j0 + t;
            s[t] = esrc[jt < jend ? jt : jend - 1];  // clamped: dup addr -> L1 hit
        }
        float ds[8];
#pragma unroll
        for (int t = 0; t < 8; ++t) ds[t] = (j0 + t < jend) ? dinv[s[t]] : 0.f;
        int4 r[8];
#pragma unroll
        for (int t = 0; t < 8; ++t)
            r[t] = *(const int4*)(Hpk + (size_t)s[t] * 64 + 4 * sub);
#pragma unroll
        for (int t = 0; t < 8; ++t) {
            const int* pr = (const int*)&r[t];
#pragma unroll
            for (int k = 0; k < 4; ++k) {
                hv2 h = __builtin_bit_cast(hv2, pr[k]);
                accl[k] = fmaf((float)h[0], ds[t], accl[k]);
                acch[k] = fmaf((float)h[1], ds[t], acch[k]);
            }
        }
    }
    float4 blo = *(const float4*)(bg + 4 * sub);
    float4 bhi = *(const float4*)(bg + 4 * sub + 64);
    *(float4*)&outh[(size_t)node * 128 + 4 * sub] =
        make_float4(fmaf(accl[0], dv, blo.x), fmaf(accl[1], dv, blo.y),
                    fmaf(accl[2], dv, blo.z), fmaf(accl[3], dv, blo.w));
    *(float4*)&outh[(size_t)node * 128 + 64 + 4 * sub] =
        make_float4(fmaf(acch[0], dv, bhi.x), fmaf(acch[1], dv, bhi.y),
                    fmaf(acch[2], dv, bhi.z), fmaf(acch[3], dv, bhi.w));
}

// ---------- Fused U/V MFMA GEMM: U = A@W1a + b1, V = A@W1b; packed (c, c+64)
__global__ __launch_bounds__(WG) void k_mm_uv(const float* __restrict__ A,
                                              const f16* __restrict__ W1t,
                                              const float* __restrict__ b1,
                                              __half2* __restrict__ Up,
                                              __half2* __restrict__ Vp, int n) {
    __shared__ f16 As[64][136];
    __shared__ f16 Bs[128][136];
    const int tid = threadIdx.x;
    const int row0 = blockIdx.x * 64;
    for (int f = tid; f < 64 * 32; f += WG) {
        int r = f >> 5, c = f & 31;
        float4 v = make_float4(0.f, 0.f, 0.f, 0.f);
        if (row0 + r < n) v = ((const float4*)A)[(size_t)(row0 + r) * 32 + c];
        *(f16x4*)&As[r][c * 4] = (f16x4){(f16)v.x, (f16)v.y, (f16)v.z, (f16)v.w};
    }
    const int wv = tid >> 6, lane = tid & 63, m = lane & 15, quad = lane >> 4;
    f32x4 acc[8];
#pragma unroll
    for (int ph = 0; ph < 2; ++ph) {
        if (ph) __syncthreads();
        for (int f = tid; f < 128 * 16; f += WG) {
            int r = f >> 4, c = f & 15;
            *(float4*)&Bs[r][c * 8] = *(const float4*)(W1t + (size_t)r * 256 + ph * 128 + c * 8);
        }
        __syncthreads();
#pragma unroll
        for (int t = 0; t < 8; ++t) acc[t] = (f32x4){0.f, 0.f, 0.f, 0.f};
#pragma unroll
        for (int kk = 0; kk < 4; ++kk) {
            f16x8 af = *(f16x8*)&As[wv * 16 + m][kk * 32 + quad * 8];
#pragma unroll
            for (int t = 0; t < 8; ++t) {
                f16x8 bf = *(f16x8*)&Bs[t * 16 + m][kk * 32 + quad * 8];
                acc[t] = __builtin_amdgcn_mfma_f32_16x16x32_f16(af, bf, acc[t], 0, 0, 0);
            }
        }
        __half2* Out = ph ? Vp : Up;
#pragma unroll
        for (int t = 0; t < 4; ++t) {
            float bl = 0.f, bh = 0.f;
            if (!ph) { bl = b1[t * 16 + m]; bh = b1[t * 16 + m + 64]; }
#pragma unroll
            for (int r = 0; r < 4; ++r) {
                int row = row0 + wv * 16 + quad * 4 + r;
                if (row < n)
                    Out[(size_t)row * 64 + t * 16 + m] =
                        __floats2half2_rn(acc[t][r] + bl, acc[t + 4][r] + bh);
            }
        }
    }
}

// --------- 4 pairs per 16-lane group (16/wave): logit = relu(U[a]+V[b]).W2 + b2
__global__ __launch_bounds__(WG) void k_pair16(const __half2* __restrict__ U,
                                               const __half2* __restrict__ V,
                                               const float* __restrict__ W2,
                                               const float* __restrict__ b2,
                                               const int* __restrict__ pairs,
                                               float* __restrict__ out_logit, int p) {
    int wv = (blockIdx.x * WG + threadIdx.x) >> 6;
    int lane = threadIdx.x & 63;
    int g = lane >> 4, sub = lane & 15;
    int qb = wv * 16 + g;  // this group: pairs qb, qb+4, qb+8, qb+12
    if (qb >= p) return;
    int q0 = qb;
    int q1 = (qb + 4 < p) ? qb + 4 : qb;
    int q2 = (qb + 8 < p) ? qb + 8 : qb;
    int q3 = (qb + 12 < p) ? qb + 12 : qb;
    int a0 = pairs[2 * q0], b0 = pairs[2 * q0 + 1];
    int a1 = pairs[2 * q1], b1i = pairs[2 * q1 + 1];
    int a2 = pairs[2 * q2], b2i = pairs[2 * q2 + 1];
    int a3 = pairs[2 * q3], b3i = pairs[2 * q3 + 1];

    // issue all 8 gather loads before any use
    int4 u0 = *(const int4*)(U + (size_t)a0 * 64 + 4 * sub);
    int4 v0 = *(const int4*)(V + (size_t)b0 * 64 + 4 * sub);
    int4 u1 = *(const int4*)(U + (size_t)a1 * 64 + 4 * sub);
    int4 v1 = *(const int4*)(V + (size_t)b1i * 64 + 4 * sub);
    int4 u2 = *(const int4*)(U + (size_t)a2 * 64 + 4 * sub);
    int4 v2 = *(const int4*)(V + (size_t)b2i * 64 + 4 * sub);
    int4 u3 = *(const int4*)(U + (size_t)a3 * 64 + 4 * sub);
    int4 v3 = *(const int4*)(V + (size_t)b3i * 64 + 4 * sub);

    float4 w2lo = ((const float4*)W2)[sub];
    float4 w2hi = ((const float4*)(W2 + 64))[sub];
    hv2 w2h[4];
    w2h[0] = hv2{(f16)w2lo.x, (f16)w2hi.x};
    w2h[1] = hv2{(f16)w2lo.y, (f16)w2hi.y};
    w2h[2] = hv2{(f16)w2lo.z, (f16)w2hi.z};
    w2h[3] = hv2{(f16)w2lo.w, (f16)w2hi.w};

    const int* ui0 = (const int*)&u0;
    const int* vi0 = (const int*)&v0;
    const int* ui1 = (const int*)&u1;
    const int* vi1 = (const int*)&v1;
    const int* ui2 = (const int*)&u2;
    const int* vi2 = (const int*)&v2;
    const int* ui3 = (const int*)&u3;
    const int* vi3 = (const int*)&v3;

    const hv2 z2 = hv2{(f16)0.f, (f16)0.f};
    float p0 = 0.f, p1 = 0.f, p2 = 0.f, p3 = 0.f;
#pragma unroll
    for (int k = 0; k < 4; ++k) {
        hv2 s0 = __builtin_bit_cast(hv2, ui0[k]) + __builtin_bit_cast(hv2, vi0[k]);
        hv2 s1 = __builtin_bit_cast(hv2, ui1[k]) + __builtin_bit_cast(hv2, vi1[k]);
        hv2 s2 = __builtin_bit_cast(hv2, ui2[k]) + __builtin_bit_cast(hv2, vi2[k]);
        hv2 s3 = __builtin_bit_cast(hv2, ui3[k]) + __builtin_bit_cast(hv2, vi3[k]);
        p0 = __builtin_amdgcn_fdot2(__builtin_elementwise_max(s0, z2), w2h[k], p0, false);
        p1 = __builtin_amdgcn_fdot2(__builtin_elementwise_max(s1, z2), w2h[k], p1, false);
        p2 = __builtin_amdgcn_fdot2(__builtin_elementwise_max(s2, z2), w2h[k], p2, false);
        p3 = __builtin_amdgcn_fdot2(__builtin_elementwise_max(s3, z2), w2h[k], p3, false);
    }
#pragma unroll
    for (int m = 1; m < 16; m <<= 1) {
        p0 += __shfl_xor(p0, m, 64);
        p1 += __shfl_xor(p1, m, 64);
        p2 += __shfl_xor(p2, m, 64);
        p3 += __shfl_xor(p3, m, 64);
    }
    if (sub == 0) {
        float bb = b2[0];
        out_logit[q0] = p0 + bb;
        if (qb + 4 < p) out_logit[qb + 4] = p1 + bb;
        if (qb + 8 < p) out_logit[qb + 8] = p2 + bb;
        if (qb + 12 < p) out_logit[qb + 12] = p3 + bb;
    }
}

extern "C" void kernel_launch(void* const* d_in, const int* in_sizes, int n_in,
                              void* d_out, int out_size, void* d_ws, size_t ws_size,
                              hipStream_t stream) {
    const float* x     = (const float*)d_in[0];
    const int*   eidx  = (const int*)d_in[1];
    const int*   pairs = (const int*)d_in[2];
    const float* W_gcn = (const float*)d_in[3];
    const float* b_gcn = (const float*)d_in[4];
    const float* W1    = (const float*)d_in[5];
    const float* b1    = (const float*)d_in[6];
    const float* W2    = (const float*)d_in[7];
    const float* b2    = (const float*)d_in[8];

    const int N = in_sizes[0] / 128;
    const int E = in_sizes[1] / 2;
    const int P = in_sizes[2] / 2;
    const int* esrc_in = eidx;
    const int* edst_in = eidx + E;

    // workspace layout (4-byte units) — same as R1 (known-good)
    float* ws      = (float*)d_ws;
    int*   deg     = (int*)d_ws;                  // [N]
    float* dinv    = ws + 65536;                  // [N]
    int*   base    = (int*)(ws + 131072);         // [N+1]
    int*   bsum    = (int*)(ws + 196608);         // [256]
    f16*   Wt_gcn  = (f16*)(ws + 197120);         // [128*128] f16
    f16*   W1t     = (f16*)(ws + 205312);         // [128*256] f16
    int*   rank    = (int*)(ws + 221696);         // [E]
    int*   ecsr    = rank + (size_t)E;            // [E]
    __half2* Hpk   = (__half2*)(ecsr + (size_t)E);  // [N*64]  (raw h, packed c,c+64)
    __half2* Upk   = Hpk + (size_t)N * 64;        // [N*64]
    __half2* Vpk   = Upk + (size_t)N * 64;        // [N*64]

    float* out_logit = (float*)d_out;             // [P]
    float* out_pairs = out_logit + P;             // [2P] as float
    float* out_h     = out_logit + 3 * (size_t)P; // [N*128]

    const int nb    = (N + WG - 1) / WG;          // 196
    const int nmm   = (N + 63) / 64;              // 782
    const int necnt = (E + WG - 1) / WG;          // 3125
    const int ncvt  = (P / 2 + WG - 1) / WG;      // 1954
    int gmax = nmm;
    int h2 = (necnt + 1) / 2;
    if (h2 > gmax) gmax = h2;
    if (ncvt > gmax) gmax = ncvt;
    dim3 blk(WG);

    hipMemsetAsync(deg, 0, (size_t)N * 4, stream);
    // transposes (Wgt consumed by fusedA, so must precede it)
    k_misc0  <<<192, blk, 0, stream>>>(W_gcn, Wt_gcn, W1, W1t);
    // A: mm_hpk (raw h) || edge histogram || pair cvt  — hides ~30us of atomics
    k_fusedA <<<4 * gmax, blk, 0, stream>>>(x, Wt_gcn, Hpk, N,
                                            edst_in, deg, rank, E,
                                            pairs, out_pairs, P / 2,
                                            nmm, necnt, ncvt);
    k_scan1  <<<nb, blk, 0, stream>>>(deg, dinv, base, bsum, N);
    k_scan23 <<<nb, blk, 0, stream>>>(base, bsum, N, E, nb);
    k_fill   <<<necnt, blk, 0, stream>>>(esrc_in, edst_in, base, rank, ecsr, E);
    k_gather <<<(N + 15) / 16, blk, 0, stream>>>(Hpk, dinv, b_gcn, base, ecsr, out_h, N);
    k_mm_uv  <<<nmm, blk, 0, stream>>>(out_h, W1t, b1, Upk, Vpk, N);
    k_pair16 <<<(P + 63) / 64, blk, 0, stream>>>(Upk, Vpk, W2, b2, pairs, out_logit, P);
}